// Round 13
// baseline (267.516 us; speedup 1.0000x reference)
//
#include <hip/hip_runtime.h>
#include <hip/hip_bf16.h>
#include <cstdint>
#include <cstddef>

#define T_SEQ 2048
#define CDIM  2048
#define HQ    16
#define HKV   4
#define DHEAD 128
#define NQKV  3072   // q(2048) | k(512) | v(512)

typedef __bf16 bf8 __attribute__((ext_vector_type(8)));
typedef __bf16 bf4 __attribute__((ext_vector_type(4)));
typedef float  f4  __attribute__((ext_vector_type(4)));

static __device__ __forceinline__ f4 mfma16(bf8 a, bf8 b, f4 c) {
    return __builtin_amdgcn_mfma_f32_16x16x32_bf16(a, b, c, 0, 0, 0);
}

#define GLOAD16(g, l)                                                        \
    __builtin_amdgcn_global_load_lds(                                        \
        (const __attribute__((address_space(1))) void*)(g),                  \
        (__attribute__((address_space(3))) void*)(l), 16, 0, 0)

// ---------------- fused prep: x->bf16, RoPE table, 4 weight transposes ----------------
__global__ __launch_bounds__(256) void k_pre(const float* __restrict__ x,
                                             const float* __restrict__ wq,
                                             const float* __restrict__ wk,
                                             const float* __restrict__ wv,
                                             const float* __restrict__ wo,
                                             __bf16* __restrict__ xbf,
                                             float* __restrict__ tab,
                                             __bf16* __restrict__ wqkvT,
                                             __bf16* __restrict__ woT) {
    const int bid = blockIdx.x, tid = threadIdx.x;
    if (bid < 4096) {
        int i = bid * 256 + tid;
        float4 v = ((const float4*)x)[i];
        bf4 o;
        o[0] = (__bf16)v.x; o[1] = (__bf16)v.y; o[2] = (__bf16)v.z; o[3] = (__bf16)v.w;
        ((bf4*)xbf)[i] = o;
        return;
    }
    if (bid < 4608) {
        int idx = (bid - 4096) * 256 + tid;  // T*64
        int t = idx >> 6, j = idx & 63;
        float invf = expf(-(float)j * (9.210340371976184f / 64.0f));
        float a = (float)t * invf;
        tab[idx * 2 + 0] = cosf(a);
        tab[idx * 2 + 1] = sinf(a);
        return;
    }
    __shared__ float tile[32][33];
    const int n = bid - 4608;
    const int bx = n % 160, by = n / 160;
    const float* src; __bf16* dst; int ld_src, cx;
    if (bx < 64)      { src = wq; dst = wqkvT;                        ld_src = 2048; cx = bx; }
    else if (bx < 80) { src = wk; dst = wqkvT + (size_t)2048 * 2048;  ld_src = 512;  cx = bx - 64; }
    else if (bx < 96) { src = wv; dst = wqkvT + (size_t)2560 * 2048;  ld_src = 512;  cx = bx - 80; }
    else              { src = wo; dst = woT;                          ld_src = 2048; cx = bx - 96; }
    const int c0 = cx * 32, r0 = by * 32;
    const int tx = tid & 31, ty = tid >> 5;
#pragma unroll
    for (int i = 0; i < 4; ++i)
        tile[ty + i * 8][tx] = src[(size_t)(r0 + ty + i * 8) * ld_src + c0 + tx];
    __syncthreads();
#pragma unroll
    for (int i = 0; i < 4; ++i)
        dst[(size_t)(c0 + ty + i * 8) * 2048 + r0 + tx] = (__bf16)tile[tx][ty + i * 8];
}

// ---------------- GEMM: C[M][N] = A[M][K] * BT[N][K]^T ----------------
// 512 thr / 8 waves (4 row x 2 col), per-wave acc[2][4] (32x128 output).
// BK=64 double-buffered global_load_lds, one barrier per K-step, XOR-swizzled LDS.
// MODE 0: fp32 C out. MODE 1: QKV fused epilogue -> RoPE'd Q/K + transposed VT.
template <int MODE>
__global__ __launch_bounds__(512, 4) void k_gemm(const __bf16* __restrict__ A,
                                                 const __bf16* __restrict__ BT,
                                                 float* __restrict__ C,
                                                 const float2* __restrict__ tab,
                                                 __bf16* __restrict__ Qo,
                                                 __bf16* __restrict__ Ko,
                                                 __bf16* __restrict__ Vo,
                                                 int M, int N, int K) {
    __shared__ __bf16 lds[2][2][128 * 64];   // [buf][mat][row*64], rows 128B
    char* L = (char*)&lds[0][0][0];
    const int tid = threadIdx.x, wid = tid >> 6, lane = tid & 63;
    const int l15 = lane & 15, lhi = lane >> 4;
    const int wr = wid >> 1, wc = wid & 1;
    const size_t arow0 = (size_t)blockIdx.y * 128;
    const size_t brow0 = (size_t)blockIdx.x * 128;

    const int sr = tid >> 3;
    const int sc8 = ((tid & 7) ^ ((tid >> 3) & 7)) * 8;
    const __bf16* Ag = A + (arow0 + sr) * K + sc8;
    const __bf16* Bg = BT + (brow0 + sr) * K + sc8;

#define GSTAGE(buf, k0)                                                          \
    {                                                                            \
        _Pragma("unroll") for (int i = 0; i < 2; ++i) {                          \
            GLOAD16(Ag + (k0) + (size_t)i * 64 * K,                              \
                    L + (buf) * 32768 + i * 8192 + tid * 16);                    \
            GLOAD16(Bg + (k0) + (size_t)i * 64 * K,                              \
                    L + (buf) * 32768 + 16384 + i * 8192 + tid * 16);            \
        }                                                                        \
    }

    f4 acc[2][4] = {};
    GSTAGE(0, 0);
    __syncthreads();
    int cur = 0;

    for (int k0 = 0; k0 < K; k0 += 64) {
        if (k0 + 64 < K) GSTAGE(cur ^ 1, k0 + 64);
        const char* Ab = L + cur * 32768;
        const char* Bb = Ab + 16384;
        bf8 af[2][2], bfr[2][4];
#pragma unroll
        for (int kk = 0; kk < 2; ++kk) {
            const int ch = ((kk * 4 + lhi) ^ (l15 & 7)) * 16;
#pragma unroll
            for (int m = 0; m < 2; ++m)
                af[kk][m] = *(const bf8*)(Ab + (wr * 32 + m * 16 + l15) * 128 + ch);
#pragma unroll
            for (int n = 0; n < 4; ++n)
                bfr[kk][n] = *(const bf8*)(Bb + (n * 32 + wc * 16 + l15) * 128 + ch);
        }
        __builtin_amdgcn_s_setprio(1);
#pragma unroll
        for (int kk = 0; kk < 2; ++kk)
#pragma unroll
            for (int m = 0; m < 2; ++m)
#pragma unroll
                for (int n = 0; n < 4; ++n)
                    acc[m][n] = mfma16(af[kk][m], bfr[kk][n], acc[m][n]);
        __builtin_amdgcn_s_setprio(0);
        __syncthreads();
        cur ^= 1;
    }
#undef GSTAGE

    const int row0 = blockIdx.y * 128 + wr * 32;
    if (MODE == 0) {
#pragma unroll
        for (int m = 0; m < 2; ++m)
#pragma unroll
            for (int n = 0; n < 4; ++n) {
                const int c = blockIdx.x * 128 + n * 32 + wc * 16 + l15;
#pragma unroll
                for (int j = 0; j < 4; ++j)
                    C[(size_t)(row0 + m * 16 + lhi * 4 + j) * N + c] = acc[m][n][j];
            }
    } else {
        const int bx = blockIdx.x;
        if (bx < 20) {
            // RoPE on fp32 acc: pair (n, n+2) = (d, d+64), d = n*32+wc*16+l15
            __bf16* dst0 = (bx < 16) ? (Qo + (size_t)bx * T_SEQ * DHEAD)
                                     : (Ko + (size_t)(bx - 16) * T_SEQ * DHEAD);
#pragma unroll
            for (int m = 0; m < 2; ++m)
#pragma unroll
                for (int n = 0; n < 2; ++n) {
                    const int d = n * 32 + wc * 16 + l15;
#pragma unroll
                    for (int j = 0; j < 4; ++j) {
                        const int t = row0 + m * 16 + lhi * 4 + j;
                        const float2 cs = tab[t * 64 + d];
                        const float a = acc[m][n][j], b = acc[m][n + 2][j];
                        dst0[(size_t)t * DHEAD + d]      = (__bf16)(a * cs.x - b * cs.y);
                        dst0[(size_t)t * DHEAD + d + 64] = (__bf16)(b * cs.x + a * cs.y);
                    }
                }
        } else {
            // V: write transposed VT[kvh][d][t], 4 consecutive t per lane
            __bf16* vdst = Vo + (size_t)(bx - 20) * DHEAD * T_SEQ;
#pragma unroll
            for (int m = 0; m < 2; ++m)
#pragma unroll
                for (int n = 0; n < 4; ++n) {
                    const int c = n * 32 + wc * 16 + l15;
                    bf4 o;
#pragma unroll
                    for (int j = 0; j < 4; ++j) o[j] = (__bf16)acc[m][n][j];
                    *(bf4*)&vdst[(size_t)c * T_SEQ + row0 + m * 16 + lhi * 4] = o;
                }
        }
    }
}

// ---------------- dual-softmax flash attention ----------------
// grid (32,16) x 512 thr (8 waves = 4 qw x 2 par key-split).
// K double-buffered in LDS (2x32KB, stage-next-before-compute, 1 barrier/round);
// V read DIRECT from global/L2 in the PV loop (64B-coalesced segments).
// 80KB LDS + launch_bounds(512,4) -> 2 blocks/CU (4 waves/SIMD TLP).
// qt = (head<8) ? 31-bx : bx (r10 pairing). Split-softmax exact merge at end.
__global__ __launch_bounds__(512, 4) void k_attn(const __bf16* __restrict__ Q,
                                                 const __bf16* __restrict__ Kr,
                                                 const __bf16* __restrict__ VT,
                                                 __bf16* __restrict__ att) {
    __shared__ __align__(16) char lds[81920];
    char* KlB  = lds;               // [2][128 keys][256B d], 4-bit row XOR swz (64KB)
    char* PlB0 = lds + 65536;       // 8 waves x 2KB

    const int h = blockIdx.y, kvh = h >> 2;
    const int qt = (blockIdx.y < 8) ? (31 - (int)blockIdx.x) : (int)blockIdx.x;
    const int tid = threadIdx.x, wid = tid >> 6, lane = tid & 63;
    const int l15 = lane & 15, lhi = lane >> 4;
    const int par = wid >> 2, qw = wid & 3;
    const int q0w = qt * 64 + qw * 16;
    const bool hasloc = qt >= 4;
    const int lfLo = 4 * (qt >> 2) - 2;
    const int lpart = qt - 2;
    const float CE = 0.12751741f;                // (1/sqrt(128)) * log2(e)
    const float L2E = 1.44269504f;
    const float SCL = 0.08838834764831845f;
    const float THR = 5.5451774f;                // 8*ln2

    char* PlB = PlB0 + wid * 2048;

    const int srow = tid >> 4;                        // 0..31
    const int sg = (((tid & 15) ^ (srow & 15)) << 3); // elem offset
    const __bf16* KgB = Kr + (size_t)kvh * T_SEQ * DHEAD;
    const __bf16* VgB = VT + (size_t)kvh * DHEAD * T_SEQ;

#define STAGE(bsel, kb2)                                                          \
    {                                                                             \
        _Pragma("unroll") for (int i = 0; i < 4; ++i) {                           \
            GLOAD16(KgB + (size_t)((kb2) + i * 32 + srow) * DHEAD + sg,           \
                    KlB + (bsel) + i * 8192 + tid * 16);                          \
        }                                                                         \
    }

    bf8 qf[4];
#pragma unroll
    for (int dc = 0; dc < 4; ++dc)
        qf[dc] = *(const bf8*)&Q[((size_t)h * T_SEQ + q0w + l15) * DHEAD + dc * 32 + lhi * 8];

    f4 oc[8] = {}, ow[8] = {};
    float mg[4], sgp[4], slp[4];
#pragma unroll
    for (int j = 0; j < 4; ++j) { mg[j] = -__builtin_inff(); sgp[j] = slp[j] = 0.f; }
    float mgmin = -__builtin_inff();

    const int R = (qt >> 1) + 1;
    STAGE(0, 0);
    __syncthreads();
    int cur = 0;

    for (int r = 0; r < R; ++r) {
        if (r + 1 < R) STAGE((cur ^ 1) * 32768, (r + 1) * 128);
        const int kt = 2 * r + par;
        if (kt <= qt) {
            const int kb = kt * 64;
            const int cb = cur * 32768;
            const int rowb = par * 64;
            // ---- QK^T ----
            f4 sc[4] = {};
            __builtin_amdgcn_s_setprio(1);
#pragma unroll
            for (int ks = 0; ks < 4; ++ks)
#pragma unroll
                for (int dc = 0; dc < 4; ++dc) {
                    bf8 kf = *(const bf8*)(KlB + cb + (rowb + ks * 16 + l15) * 256 +
                                           (((dc * 4 + lhi) ^ l15) << 4));
                    sc[ks] = mfma16(qf[dc], kf, sc[ks]);
                }
            __builtin_amdgcn_s_setprio(0);

            float t[4][4];
#pragma unroll
            for (int ks = 0; ks < 4; ++ks)
#pragma unroll
                for (int j = 0; j < 4; ++j) t[ks][j] = sc[ks][j];
            if (kt == qt) {  // causal mask (last tile only)
#pragma unroll
                for (int ks = 0; ks < 4; ++ks)
#pragma unroll
                    for (int j = 0; j < 4; ++j)
                        if (kb + ks * 16 + l15 > q0w + lhi * 4 + j) t[ks][j] = -3.0e38f;
            }
            // ---- single defer-max gate ----
            float mx = t[0][0];
#pragma unroll
            for (int ks = 0; ks < 4; ++ks)
#pragma unroll
                for (int j = 0; j < 4; ++j) mx = fmaxf(mx, t[ks][j]);
            mx *= SCL;
            if (!__all(mx <= mgmin + THR)) {
#pragma unroll
                for (int j = 0; j < 4; ++j) {
                    float m2 = fmaxf(fmaxf(t[0][j], t[1][j]), fmaxf(t[2][j], t[3][j])) * SCL;
#pragma unroll
                    for (int x = 1; x < 16; x <<= 1) m2 = fmaxf(m2, __shfl_xor(m2, x));
                    float mn = fmaxf(mg[j], m2);
                    float f = __builtin_amdgcn_exp2f((mg[j] - mn) * L2E);
                    mg[j] = mn;
                    sgp[j] *= f; slp[j] *= f;
#pragma unroll
                    for (int nd = 0; nd < 8; ++nd) { oc[nd][j] *= f; ow[nd][j] *= f; }
                }
                mgmin = fminf(fminf(mg[0], mg[1]), fminf(mg[2], mg[3]));
            }
            // ---- branch-free exp ----
            float p[4][4], psum[4];
#pragma unroll
            for (int j = 0; j < 4; ++j) {
                const float bj = mg[j] * L2E;
#pragma unroll
                for (int ks = 0; ks < 4; ++ks)
                    p[ks][j] = __builtin_amdgcn_exp2f(t[ks][j] * CE - bj);
                psum[j] = (p[0][j] + p[1][j]) + (p[2][j] + p[3][j]);
                sgp[j] += psum[j];
            }
            // ---- P stores (complement at the partial tile) ----
            const bool part = hasloc && (kt == lpart);
            const int e = q0w + lhi * 4 - 128 - kb - l15;  // window: ks*16 <= e+j
            if (!part) {
#pragma unroll
                for (int j = 0; j < 4; ++j) {
                    const int rsw = ((lhi * 4 + j) & 7) << 4;
                    const int rb = (lhi * 4 + j) * 128;
#pragma unroll
                    for (int ks = 0; ks < 4; ++ks)
                        *(__bf16*)(PlB + rb + ((ks * 32 + 2 * l15) ^ rsw)) = (__bf16)p[ks][j];
                }
            } else {
#pragma unroll
                for (int j = 0; j < 4; ++j) {
                    const int rsw = ((lhi * 4 + j) & 7) << 4;
                    const int rb = (lhi * 4 + j) * 128;
                    float lsum = 0.f;
#pragma unroll
                    for (int ks = 0; ks < 4; ++ks) {
                        float l = (ks * 16 <= e + j) ? p[ks][j] : 0.f;
                        lsum += l;
                        *(__bf16*)(PlB + rb + ((ks * 32 + 2 * l15) ^ rsw)) = (__bf16)(p[ks][j] - l);
                    }
                    slp[j] += lsum;
                }
            }
            const bool inwin = hasloc && kt >= lfLo && kt < lpart;
            if (inwin) {
#pragma unroll
                for (int j = 0; j < 4; ++j) slp[j] += psum[j];
            }
            // ---- PV: V direct from global (L2-resident; 64B-coalesced) ----
            const int psw = (l15 & 7) << 4;
            bf8 pf0 = *(const bf8*)(PlB + l15 * 128 + ((lhi << 4) ^ psw));
            bf8 pf1 = *(const bf8*)(PlB + l15 * 128 + ((64 + (lhi << 4)) ^ psw));
            const __bf16* Vb = VgB + kb + lhi * 8;
            __builtin_amdgcn_s_setprio(1);
            if (part) {
                // reuse Pl: overwrite with masked-local values, then load pw
#pragma unroll
                for (int j = 0; j < 4; ++j) {
                    const int rsw = ((lhi * 4 + j) & 7) << 4;
                    const int rb = (lhi * 4 + j) * 128;
#pragma unroll
                    for (int ks = 0; ks < 4; ++ks) {
                        float l = (ks * 16 <= e + j) ? p[ks][j] : 0.f;
                        *(__bf16*)(PlB + rb + ((ks * 32 + 2 * l15) ^ rsw)) = (__bf16)l;
                    }
                }
                bf8 pw0 = *(const bf8*)(PlB + l15 * 128 + ((lhi << 4) ^ psw));
                bf8 pw1 = *(const bf8*)(PlB + l15 * 128 + ((64 + (lhi << 4)) ^ psw));
#pragma unroll
                for (int nd = 0; nd < 8; ++nd) {
                    bf8 v0 = *(const bf8*)&Vb[(size_t)(nd * 16 + l15) * T_SEQ];
                    bf8 v1 = *(const bf8*)&Vb[(size_t)(nd * 16 + l15) * T_SEQ + 32];
                    oc[nd] = mfma16(pf0, v0, oc[nd]);
                    oc[nd] = mfma16(pf1, v1, oc[nd]);
                    ow[nd] = mfma16(pw0, v0, ow[nd]);
                    ow[nd] = mfma16(pw1, v1, ow[nd]);
                }
            } else if (inwin) {
#pragma unroll
                for (int nd = 0; nd < 8; ++nd) {
                    bf8 v0 = *(const bf8*)&Vb[(size_t)(nd * 16 + l15) * T_SEQ];
                    bf8 v1 = *(const bf8*)&Vb[(size_t)(nd * 16 + l15) * T_SEQ + 32];
                    ow[nd] = mfma16(pf0, v0, ow[nd]);
                    ow[nd] = mfma16(pf1, v1, ow[nd]);
                }
            } else {
#pragma unroll
                for (int nd = 0; nd < 8; ++nd) {
                    bf8 v0 = *(const bf8*)&Vb[(size_t)(nd * 16 + l15) * T_SEQ];
                    bf8 v1 = *(const bf8*)&Vb[(size_t)(nd * 16 + l15) * T_SEQ + 32];
                    oc[nd] = mfma16(pf0, v0, oc[nd]);
                    oc[nd] = mfma16(pf1, v1, oc[nd]);
                }
            }
            __builtin_amdgcn_s_setprio(0);
        }
        __syncthreads();   // drains staging (vmcnt 0) + frees cur buffer
        cur ^= 1;
    }

    // ---- split-softmax merge: waves 4-7 -> LDS, waves 0-3 combine ----
    // scratch reuses the whole LDS (304B stride -> ~8-way banking max)
    char* sb = lds + (size_t)(qw * 64 + lane) * 304;
    if (par) {
#pragma unroll
        for (int nd = 0; nd < 8; ++nd) *(f4*)(sb + nd * 16) = oc[nd];
#pragma unroll
        for (int nd = 0; nd < 8; ++nd) *(f4*)(sb + 128 + nd * 16) = ow[nd];
        f4 a, b, c;
#pragma unroll
        for (int j = 0; j < 4; ++j) { a[j] = mg[j]; b[j] = sgp[j]; c[j] = slp[j]; }
        *(f4*)(sb + 256) = a; *(f4*)(sb + 272) = b; *(f4*)(sb + 288) = c;
    }
    __syncthreads();
    if (!par) {
        f4 mB = *(const f4*)(sb + 256);
        f4 sB = *(const f4*)(sb + 272);
        f4 lB = *(const f4*)(sb + 288);
        float fA[4], fB[4];
#pragma unroll
        for (int j = 0; j < 4; ++j) {
            float ms = fmaxf(mg[j], mB[j]);
            fA[j] = __builtin_amdgcn_exp2f((mg[j] - ms) * L2E);
            fB[j] = __builtin_amdgcn_exp2f((mB[j] - ms) * L2E);
            sgp[j] = sgp[j] * fA[j] + sB[j] * fB[j];
            slp[j] = slp[j] * fA[j] + lB[j] * fB[j];
        }
#pragma unroll
        for (int nd = 0; nd < 8; ++nd) {
            f4 ocB = *(const f4*)(sb + nd * 16);
            f4 owB = *(const f4*)(sb + 128 + nd * 16);
#pragma unroll
            for (int j = 0; j < 4; ++j) {
                oc[nd][j] = oc[nd][j] * fA[j] + ocB[j] * fB[j];
                ow[nd][j] = ow[nd][j] * fA[j] + owB[j] * fB[j];
            }
        }
#pragma unroll
        for (int j = 0; j < 4; ++j) {
#pragma unroll
            for (int x = 1; x < 16; x <<= 1) {
                sgp[j] += __shfl_xor(sgp[j], x);
                slp[j] += __shfl_xor(slp[j], x);
            }
        }
        float rg[4], rl[4];
#pragma unroll
        for (int j = 0; j < 4; ++j) {
            rg[j] = 1.f / sgp[j];
            rl[j] = hasloc ? 0.5f / slp[j] : 0.f;
        }
#pragma unroll
        for (int nd = 0; nd < 8; ++nd)
#pragma unroll
            for (int j = 0; j < 4; ++j) {
                int q = q0w + lhi * 4 + j;
                float go = oc[nd][j] + ow[nd][j];
                float v = hasloc ? (go * (0.5f * rg[j]) + ow[nd][j] * rl[j]) : go * rg[j];
                att[(size_t)q * CDIM + h * DHEAD + nd * 16 + l15] = (__bf16)v;
            }
    }
#undef STAGE
}

// ---------------- launcher ----------------
extern "C" void kernel_launch(void* const* d_in, const int* in_sizes, int n_in,
                              void* d_out, int out_size, void* d_ws, size_t ws_size,
                              hipStream_t stream) {
    const float* x  = (const float*)d_in[0];
    const float* wq = (const float*)d_in[1];
    const float* wk = (const float*)d_in[2];
    const float* wv = (const float*)d_in[3];
    const float* wo = (const float*)d_in[4];
    char* ws = (char*)d_ws;

    __bf16* xbf   = (__bf16*)(ws + 0);          // 8 MB
    __bf16* wqkvT = (__bf16*)(ws + 8388608);    // 12 MB  [3072][2048]
    __bf16* woT   = (__bf16*)(ws + 20971520);   // 8 MB   [2048][2048]
    __bf16* Q     = (__bf16*)(ws + 41943040);   // 8 MB   [16][2048][128]
    __bf16* K     = (__bf16*)(ws + 50331648);   // 2 MB   [4][2048][128]
    __bf16* VTb   = (__bf16*)(ws + 52428800);   // 2 MB   [4][128][2048]
    __bf16* att   = (__bf16*)(ws + 54525952);   // 8 MB   [2048][2048]
    float*  tab   = (float*)(ws + 62914560);    // 1 MB   [2048][64][2]

    k_pre<<<14848, 256, 0, stream>>>(x, wq, wk, wv, wo, xbf, tab, wqkvT, woT);
    k_gemm<1><<<dim3(24, 16), 512, 0, stream>>>(xbf, wqkvT, nullptr, (const float2*)tab,
                                                Q, K, VTb, 2048, 3072, 2048);
    k_attn<<<dim3(32, 16), 512, 0, stream>>>(Q, K, VTb, att);
    k_gemm<0><<<dim3(16, 16), 512, 0, stream>>>(att, woT, (float*)d_out, nullptr,
                                                nullptr, nullptr, nullptr, 2048, 2048, 2048);
}

// Round 14
// 138.066 us; speedup vs baseline: 1.9376x; 1.9376x over previous
//
#include <hip/hip_runtime.h>
#include <hip/hip_bf16.h>
#include <cstdint>
#include <cstddef>

#define T_SEQ 2048
#define CDIM  2048
#define HQ    16
#define HKV   4
#define DHEAD 128
#define NQKV  3072   // q(2048) | k(512) | v(512)

typedef __bf16 bf8 __attribute__((ext_vector_type(8)));
typedef __bf16 bf4 __attribute__((ext_vector_type(4)));
typedef float  f4  __attribute__((ext_vector_type(4)));

static __device__ __forceinline__ f4 mfma16(bf8 a, bf8 b, f4 c) {
    return __builtin_amdgcn_mfma_f32_16x16x32_bf16(a, b, c, 0, 0, 0);
}

#define GLOAD16(g, l)                                                        \
    __builtin_amdgcn_global_load_lds(                                        \
        (const __attribute__((address_space(1))) void*)(g),                  \
        (__attribute__((address_space(3))) void*)(l), 16, 0, 0)

// ---------------- fused prep: x->bf16, RoPE table, 4 weight transposes ----------------
__global__ __launch_bounds__(256) void k_pre(const float* __restrict__ x,
                                             const float* __restrict__ wq,
                                             const float* __restrict__ wk,
                                             const float* __restrict__ wv,
                                             const float* __restrict__ wo,
                                             __bf16* __restrict__ xbf,
                                             float* __restrict__ tab,
                                             __bf16* __restrict__ wqkvT,
                                             __bf16* __restrict__ woT) {
    const int bid = blockIdx.x, tid = threadIdx.x;
    if (bid < 4096) {
        int i = bid * 256 + tid;
        float4 v = ((const float4*)x)[i];
        bf4 o;
        o[0] = (__bf16)v.x; o[1] = (__bf16)v.y; o[2] = (__bf16)v.z; o[3] = (__bf16)v.w;
        ((bf4*)xbf)[i] = o;
        return;
    }
    if (bid < 4608) {
        int idx = (bid - 4096) * 256 + tid;  // T*64
        int t = idx >> 6, j = idx & 63;
        float invf = expf(-(float)j * (9.210340371976184f / 64.0f));
        float a = (float)t * invf;
        tab[idx * 2 + 0] = cosf(a);
        tab[idx * 2 + 1] = sinf(a);
        return;
    }
    __shared__ float tile[32][33];
    const int n = bid - 4608;
    const int bx = n % 160, by = n / 160;
    const float* src; __bf16* dst; int ld_src, cx;
    if (bx < 64)      { src = wq; dst = wqkvT;                        ld_src = 2048; cx = bx; }
    else if (bx < 80) { src = wk; dst = wqkvT + (size_t)2048 * 2048;  ld_src = 512;  cx = bx - 64; }
    else if (bx < 96) { src = wv; dst = wqkvT + (size_t)2560 * 2048;  ld_src = 512;  cx = bx - 80; }
    else              { src = wo; dst = woT;                          ld_src = 2048; cx = bx - 96; }
    const int c0 = cx * 32, r0 = by * 32;
    const int tx = tid & 31, ty = tid >> 5;
#pragma unroll
    for (int i = 0; i < 4; ++i)
        tile[ty + i * 8][tx] = src[(size_t)(r0 + ty + i * 8) * ld_src + c0 + tx];
    __syncthreads();
#pragma unroll
    for (int i = 0; i < 4; ++i)
        dst[(size_t)(c0 + ty + i * 8) * 2048 + r0 + tx] = (__bf16)tile[tx][ty + i * 8];
}

// ---------------- GEMM: C[M][N] = A[M][K] * BT[N][K]^T ----------------
// 512 thr / 8 waves (4 row x 2 col), per-wave acc[2][4] (32x128 output).
// BK=64 double-buffered global_load_lds, one barrier per K-step, XOR-swizzled LDS.
// MODE 0: fp32 C out. MODE 1: QKV fused epilogue -> RoPE'd Q/K + transposed VT.
template <int MODE>
__global__ __launch_bounds__(512, 4) void k_gemm(const __bf16* __restrict__ A,
                                                 const __bf16* __restrict__ BT,
                                                 float* __restrict__ C,
                                                 const float2* __restrict__ tab,
                                                 __bf16* __restrict__ Qo,
                                                 __bf16* __restrict__ Ko,
                                                 __bf16* __restrict__ Vo,
                                                 int M, int N, int K) {
    __shared__ __bf16 lds[2][2][128 * 64];   // [buf][mat][row*64], rows 128B
    char* L = (char*)&lds[0][0][0];
    const int tid = threadIdx.x, wid = tid >> 6, lane = tid & 63;
    const int l15 = lane & 15, lhi = lane >> 4;
    const int wr = wid >> 1, wc = wid & 1;
    const size_t arow0 = (size_t)blockIdx.y * 128;
    const size_t brow0 = (size_t)blockIdx.x * 128;

    const int sr = tid >> 3;
    const int sc8 = ((tid & 7) ^ ((tid >> 3) & 7)) * 8;
    const __bf16* Ag = A + (arow0 + sr) * K + sc8;
    const __bf16* Bg = BT + (brow0 + sr) * K + sc8;

#define GSTAGE(buf, k0)                                                          \
    {                                                                            \
        _Pragma("unroll") for (int i = 0; i < 2; ++i) {                          \
            GLOAD16(Ag + (k0) + (size_t)i * 64 * K,                              \
                    L + (buf) * 32768 + i * 8192 + tid * 16);                    \
            GLOAD16(Bg + (k0) + (size_t)i * 64 * K,                              \
                    L + (buf) * 32768 + 16384 + i * 8192 + tid * 16);            \
        }                                                                        \
    }

    f4 acc[2][4] = {};
    GSTAGE(0, 0);
    __syncthreads();
    int cur = 0;

    for (int k0 = 0; k0 < K; k0 += 64) {
        if (k0 + 64 < K) GSTAGE(cur ^ 1, k0 + 64);
        const char* Ab = L + cur * 32768;
        const char* Bb = Ab + 16384;
        bf8 af[2][2], bfr[2][4];
#pragma unroll
        for (int kk = 0; kk < 2; ++kk) {
            const int ch = ((kk * 4 + lhi) ^ (l15 & 7)) * 16;
#pragma unroll
            for (int m = 0; m < 2; ++m)
                af[kk][m] = *(const bf8*)(Ab + (wr * 32 + m * 16 + l15) * 128 + ch);
#pragma unroll
            for (int n = 0; n < 4; ++n)
                bfr[kk][n] = *(const bf8*)(Bb + (n * 32 + wc * 16 + l15) * 128 + ch);
        }
        __builtin_amdgcn_s_setprio(1);
#pragma unroll
        for (int kk = 0; kk < 2; ++kk)
#pragma unroll
            for (int m = 0; m < 2; ++m)
#pragma unroll
                for (int n = 0; n < 4; ++n)
                    acc[m][n] = mfma16(af[kk][m], bfr[kk][n], acc[m][n]);
        __builtin_amdgcn_s_setprio(0);
        __syncthreads();
        cur ^= 1;
    }
#undef GSTAGE

    const int row0 = blockIdx.y * 128 + wr * 32;
    if (MODE == 0) {
#pragma unroll
        for (int m = 0; m < 2; ++m)
#pragma unroll
            for (int n = 0; n < 4; ++n) {
                const int c = blockIdx.x * 128 + n * 32 + wc * 16 + l15;
#pragma unroll
                for (int j = 0; j < 4; ++j)
                    C[(size_t)(row0 + m * 16 + lhi * 4 + j) * N + c] = acc[m][n][j];
            }
    } else {
        const int bx = blockIdx.x;
        if (bx < 20) {
            // RoPE on fp32 acc: pair (n, n+2) = (d, d+64), d = n*32+wc*16+l15
            __bf16* dst0 = (bx < 16) ? (Qo + (size_t)bx * T_SEQ * DHEAD)
                                     : (Ko + (size_t)(bx - 16) * T_SEQ * DHEAD);
#pragma unroll
            for (int m = 0; m < 2; ++m)
#pragma unroll
                for (int n = 0; n < 2; ++n) {
                    const int d = n * 32 + wc * 16 + l15;
#pragma unroll
                    for (int j = 0; j < 4; ++j) {
                        const int t = row0 + m * 16 + lhi * 4 + j;
                        const float2 cs = tab[t * 64 + d];
                        const float a = acc[m][n][j], b = acc[m][n + 2][j];
                        dst0[(size_t)t * DHEAD + d]      = (__bf16)(a * cs.x - b * cs.y);
                        dst0[(size_t)t * DHEAD + d + 64] = (__bf16)(b * cs.x + a * cs.y);
                    }
                }
        } else {
            // V: write transposed VT[kvh][d][t], 4 consecutive t per lane
            __bf16* vdst = Vo + (size_t)(bx - 20) * DHEAD * T_SEQ;
#pragma unroll
            for (int m = 0; m < 2; ++m)
#pragma unroll
                for (int n = 0; n < 4; ++n) {
                    const int c = n * 32 + wc * 16 + l15;
                    bf4 o;
#pragma unroll
                    for (int j = 0; j < 4; ++j) o[j] = (__bf16)acc[m][n][j];
                    *(bf4*)&vdst[(size_t)c * T_SEQ + row0 + m * 16 + lhi * 4] = o;
                }
        }
    }
}

// ---------------- dual-softmax flash attention, key-split across wave halves ----------------
// grid (32,16) x 512 thr (8 waves). Waves 0-3: even key tiles; 4-7: odd key tiles,
// same 64 q-rows. Per-half online softmax; exact merge at end. K/V double-buffered
// 128-key rounds via global_load_lds (pre-swizzled source).
__global__ __launch_bounds__(512) void k_attn(const __bf16* __restrict__ Q,
                                              const __bf16* __restrict__ Kr,
                                              const __bf16* __restrict__ VT,
                                              __bf16* __restrict__ att) {
    __shared__ __align__(16) char lds[155648];
    char* KlB  = lds;               // [2][128 keys][256B d], 4-bit row XOR swz
    char* VlB  = lds + 65536;       // [2][128 d][256B keys], 4-bit row XOR swz
    char* PlB0 = lds + 131072;      // 8 waves x 2KB
    char* PwB0 = lds + 147456;      // 4 qw x 2KB (parity-active waves only)

    const int h = blockIdx.y, kvh = h >> 2;
    const int qt = (blockIdx.y < 8) ? (31 - (int)blockIdx.x) : (int)blockIdx.x;
    const int tid = threadIdx.x, wid = tid >> 6, lane = tid & 63;
    const int l15 = lane & 15, lhi = lane >> 4;
    const int par = wid >> 2, qw = wid & 3;
    const int q0w = qt * 64 + qw * 16;
    const bool hasloc = qt >= 4;
    const int lfLo = 4 * (qt >> 2) - 2;
    const int lpart = qt - 2;
    const float CE = 0.12751741f;                // (1/sqrt(128)) * log2(e)
    const float L2E = 1.44269504f;
    const float SCL = 0.08838834764831845f;
    const float THR = 5.5451774f;                // 8*ln2

    char* PlB = PlB0 + wid * 2048;
    char* PwB = PwB0 + qw * 2048;

    const int srow = tid >> 4;                        // 0..31
    const int sg = (((tid & 15) ^ (srow & 15)) << 3); // elem offset
    const __bf16* KgB = Kr + (size_t)kvh * T_SEQ * DHEAD;
    const __bf16* VgB = VT + (size_t)kvh * DHEAD * T_SEQ;

#define STAGE(bsel, kb2)                                                          \
    {                                                                             \
        _Pragma("unroll") for (int i = 0; i < 4; ++i) {                           \
            GLOAD16(KgB + (size_t)((kb2) + i * 32 + srow) * DHEAD + sg,           \
                    KlB + (bsel) + i * 8192 + tid * 16);                          \
            GLOAD16(VgB + (size_t)(i * 32 + srow) * T_SEQ + (kb2) + sg,           \
                    VlB + (bsel) + i * 8192 + tid * 16);                          \
        }                                                                         \
    }

    bf8 qf[4];
#pragma unroll
    for (int dc = 0; dc < 4; ++dc)
        qf[dc] = *(const bf8*)&Q[((size_t)h * T_SEQ + q0w + l15) * DHEAD + dc * 32 + lhi * 8];

    f4 oc[8] = {}, ow[8] = {};
    float mg[4], sgp[4], slp[4];
#pragma unroll
    for (int j = 0; j < 4; ++j) { mg[j] = -__builtin_inff(); sgp[j] = slp[j] = 0.f; }
    float mgmin = -__builtin_inff();

    const int R = (qt >> 1) + 1;
    STAGE(0, 0);
    __syncthreads();
    int cur = 0;

    for (int r = 0; r < R; ++r) {
        if (r + 1 < R) STAGE((cur ^ 1) * 32768, (r + 1) * 128);
        const int kt = 2 * r + par;
        if (kt <= qt) {
            const int kb = kt * 64;
            const int cb = cur * 32768;
            const int rowb = par * 64;
            // ---- QK^T ----
            f4 sc[4] = {};
            __builtin_amdgcn_s_setprio(1);
#pragma unroll
            for (int ks = 0; ks < 4; ++ks)
#pragma unroll
                for (int dc = 0; dc < 4; ++dc) {
                    bf8 kf = *(const bf8*)(KlB + cb + (rowb + ks * 16 + l15) * 256 +
                                           (((dc * 4 + lhi) ^ l15) << 4));
                    sc[ks] = mfma16(qf[dc], kf, sc[ks]);
                }
            __builtin_amdgcn_s_setprio(0);

            float t[4][4];
#pragma unroll
            for (int ks = 0; ks < 4; ++ks)
#pragma unroll
                for (int j = 0; j < 4; ++j) t[ks][j] = sc[ks][j];
            if (kt == qt) {  // causal mask (last tile only)
#pragma unroll
                for (int ks = 0; ks < 4; ++ks)
#pragma unroll
                    for (int j = 0; j < 4; ++j)
                        if (kb + ks * 16 + l15 > q0w + lhi * 4 + j) t[ks][j] = -3.0e38f;
            }
            // ---- single defer-max gate ----
            float mx = t[0][0];
#pragma unroll
            for (int ks = 0; ks < 4; ++ks)
#pragma unroll
                for (int j = 0; j < 4; ++j) mx = fmaxf(mx, t[ks][j]);
            mx *= SCL;
            if (!__all(mx <= mgmin + THR)) {
#pragma unroll
                for (int j = 0; j < 4; ++j) {
                    float m2 = fmaxf(fmaxf(t[0][j], t[1][j]), fmaxf(t[2][j], t[3][j])) * SCL;
#pragma unroll
                    for (int x = 1; x < 16; x <<= 1) m2 = fmaxf(m2, __shfl_xor(m2, x));
                    float mn = fmaxf(mg[j], m2);
                    float f = __builtin_amdgcn_exp2f((mg[j] - mn) * L2E);
                    mg[j] = mn;
                    sgp[j] *= f; slp[j] *= f;
#pragma unroll
                    for (int nd = 0; nd < 8; ++nd) { oc[nd][j] *= f; ow[nd][j] *= f; }
                }
                mgmin = fminf(fminf(mg[0], mg[1]), fminf(mg[2], mg[3]));
            }
            // ---- branch-free exp ----
            float p[4][4], psum[4];
#pragma unroll
            for (int j = 0; j < 4; ++j) {
                const float bj = mg[j] * L2E;
#pragma unroll
                for (int ks = 0; ks < 4; ++ks)
                    p[ks][j] = __builtin_amdgcn_exp2f(t[ks][j] * CE - bj);
                psum[j] = (p[0][j] + p[1][j]) + (p[2][j] + p[3][j]);
                sgp[j] += psum[j];
            }
            // ---- P stores ----
            const bool part = hasloc && (kt == lpart);
            if (!part) {
#pragma unroll
                for (int j = 0; j < 4; ++j) {
                    const int rsw = ((lhi * 4 + j) & 7) << 4;
                    const int rb = (lhi * 4 + j) * 128;
#pragma unroll
                    for (int ks = 0; ks < 4; ++ks)
                        *(__bf16*)(PlB + rb + ((ks * 32 + 2 * l15) ^ rsw)) = (__bf16)p[ks][j];
                }
            } else {
                const int e = q0w + lhi * 4 - 128 - kb - l15;
#pragma unroll
                for (int j = 0; j < 4; ++j) {
                    const int rsw = ((lhi * 4 + j) & 7) << 4;
                    const int rb = (lhi * 4 + j) * 128;
                    float lsum = 0.f;
#pragma unroll
                    for (int ks = 0; ks < 4; ++ks) {
                        float l = (ks * 16 <= e + j) ? p[ks][j] : 0.f;
                        lsum += l;
                        *(__bf16*)(PwB + rb + ((ks * 32 + 2 * l15) ^ rsw)) = (__bf16)l;
                        *(__bf16*)(PlB + rb + ((ks * 32 + 2 * l15) ^ rsw)) = (__bf16)(p[ks][j] - l);
                    }
                    slp[j] += lsum;
                }
            }
            const bool inwin = hasloc && kt >= lfLo && kt < lpart;
            if (inwin) {
#pragma unroll
                for (int j = 0; j < 4; ++j) slp[j] += psum[j];
            }
            // ---- PV ----
            const int psw = (l15 & 7) << 4;
            bf8 pf0 = *(const bf8*)(PlB + l15 * 128 + ((lhi << 4) ^ psw));
            bf8 pf1 = *(const bf8*)(PlB + l15 * 128 + ((64 + (lhi << 4)) ^ psw));
            const int vg0 = ((par * 8 + lhi) ^ l15) << 4;
            const int vg1 = ((par * 8 + 4 + lhi) ^ l15) << 4;
            __builtin_amdgcn_s_setprio(1);
            if (part) {
                bf8 pw0 = *(const bf8*)(PwB + l15 * 128 + ((lhi << 4) ^ psw));
                bf8 pw1 = *(const bf8*)(PwB + l15 * 128 + ((64 + (lhi << 4)) ^ psw));
#pragma unroll
                for (int nd = 0; nd < 8; ++nd) {
                    bf8 v0 = *(const bf8*)(VlB + cb + (nd * 16 + l15) * 256 + vg0);
                    bf8 v1 = *(const bf8*)(VlB + cb + (nd * 16 + l15) * 256 + vg1);
                    oc[nd] = mfma16(pf0, v0, oc[nd]);
                    oc[nd] = mfma16(pf1, v1, oc[nd]);
                    ow[nd] = mfma16(pw0, v0, ow[nd]);
                    ow[nd] = mfma16(pw1, v1, ow[nd]);
                }
            } else if (inwin) {
#pragma unroll
                for (int nd = 0; nd < 8; ++nd) {
                    bf8 v0 = *(const bf8*)(VlB + cb + (nd * 16 + l15) * 256 + vg0);
                    bf8 v1 = *(const bf8*)(VlB + cb + (nd * 16 + l15) * 256 + vg1);
                    ow[nd] = mfma16(pf0, v0, ow[nd]);
                    ow[nd] = mfma16(pf1, v1, ow[nd]);
                }
            } else {
#pragma unroll
                for (int nd = 0; nd < 8; ++nd) {
                    bf8 v0 = *(const bf8*)(VlB + cb + (nd * 16 + l15) * 256 + vg0);
                    bf8 v1 = *(const bf8*)(VlB + cb + (nd * 16 + l15) * 256 + vg1);
                    oc[nd] = mfma16(pf0, v0, oc[nd]);
                    oc[nd] = mfma16(pf1, v1, oc[nd]);
                }
            }
            __builtin_amdgcn_s_setprio(0);
        }
        __syncthreads();   // drains staging (vmcnt 0) + frees cur buffer
        cur ^= 1;
    }

    // ---- split-softmax merge: waves 4-7 -> LDS, waves 0-3 combine ----
    if (par) {
        char* sb = lds + qw * 20480 + lane * 320;
#pragma unroll
        for (int nd = 0; nd < 8; ++nd) *(f4*)(sb + nd * 16) = oc[nd];
#pragma unroll
        for (int nd = 0; nd < 8; ++nd) *(f4*)(sb + 128 + nd * 16) = ow[nd];
        f4 a, b, c;
#pragma unroll
        for (int j = 0; j < 4; ++j) { a[j] = mg[j]; b[j] = sgp[j]; c[j] = slp[j]; }
        *(f4*)(sb + 256) = a; *(f4*)(sb + 272) = b; *(f4*)(sb + 288) = c;
    }
    __syncthreads();
    if (!par) {
        char* sb = lds + qw * 20480 + lane * 320;
        f4 mB = *(const f4*)(sb + 256);
        f4 sB = *(const f4*)(sb + 272);
        f4 lB = *(const f4*)(sb + 288);
        float fA[4], fB[4];
#pragma unroll
        for (int j = 0; j < 4; ++j) {
            float ms = fmaxf(mg[j], mB[j]);
            fA[j] = __builtin_amdgcn_exp2f((mg[j] - ms) * L2E);
            fB[j] = __builtin_amdgcn_exp2f((mB[j] - ms) * L2E);
            sgp[j] = sgp[j] * fA[j] + sB[j] * fB[j];
            slp[j] = slp[j] * fA[j] + lB[j] * fB[j];
        }
#pragma unroll
        for (int nd = 0; nd < 8; ++nd) {
            f4 ocB = *(const f4*)(sb + nd * 16);
            f4 owB = *(const f4*)(sb + 128 + nd * 16);
#pragma unroll
            for (int j = 0; j < 4; ++j) {
                oc[nd][j] = oc[nd][j] * fA[j] + ocB[j] * fB[j];
                ow[nd][j] = ow[nd][j] * fA[j] + owB[j] * fB[j];
            }
        }
#pragma unroll
        for (int j = 0; j < 4; ++j) {
#pragma unroll
            for (int x = 1; x < 16; x <<= 1) {
                sgp[j] += __shfl_xor(sgp[j], x);
                slp[j] += __shfl_xor(slp[j], x);
            }
        }
        float rg[4], rl[4];
#pragma unroll
        for (int j = 0; j < 4; ++j) {
            rg[j] = 1.f / sgp[j];
            rl[j] = hasloc ? 0.5f / slp[j] : 0.f;
        }
#pragma unroll
        for (int nd = 0; nd < 8; ++nd)
#pragma unroll
            for (int j = 0; j < 4; ++j) {
                int q = q0w + lhi * 4 + j;
                float go = oc[nd][j] + ow[nd][j];
                float v = hasloc ? (go * (0.5f * rg[j]) + ow[nd][j] * rl[j]) : go * rg[j];
                att[(size_t)q * CDIM + h * DHEAD + nd * 16 + l15] = (__bf16)v;
            }
    }
#undef STAGE
}

// ---------------- launcher ----------------
extern "C" void kernel_launch(void* const* d_in, const int* in_sizes, int n_in,
                              void* d_out, int out_size, void* d_ws, size_t ws_size,
                              hipStream_t stream) {
    const float* x  = (const float*)d_in[0];
    const float* wq = (const float*)d_in[1];
    const float* wk = (const float*)d_in[2];
    const float* wv = (const float*)d_in[3];
    const float* wo = (const float*)d_in[4];
    char* ws = (char*)d_ws;

    __bf16* xbf   = (__bf16*)(ws + 0);          // 8 MB
    __bf16* wqkvT = (__bf16*)(ws + 8388608);    // 12 MB  [3072][2048]
    __bf16* woT   = (__bf16*)(ws + 20971520);   // 8 MB   [2048][2048]
    __bf16* Q     = (__bf16*)(ws + 41943040);   // 8 MB   [16][2048][128]
    __bf16* K     = (__bf16*)(ws + 50331648);   // 2 MB   [4][2048][128]
    __bf16* VTb   = (__bf16*)(ws + 52428800);   // 2 MB   [4][128][2048]
    __bf16* att   = (__bf16*)(ws + 54525952);   // 8 MB   [2048][2048]
    float*  tab   = (float*)(ws + 62914560);    // 1 MB   [2048][64][2]

    k_pre<<<14848, 256, 0, stream>>>(x, wq, wk, wv, wo, xbf, tab, wqkvT, woT);
    k_gemm<1><<<dim3(24, 16), 512, 0, stream>>>(xbf, wqkvT, nullptr, (const float2*)tab,
                                                Q, K, VTb, 2048, 3072, 2048);
    k_attn<<<dim3(32, 16), 512, 0, stream>>>(Q, K, VTb, att);
    k_gemm<0><<<dim3(16, 16), 512, 0, stream>>>(att, woT, (float*)d_out, nullptr,
                                                nullptr, nullptr, nullptr, 2048, 2048, 2048);
}

// Round 16
// 137.544 us; speedup vs baseline: 1.9450x; 1.0038x over previous
//
#include <hip/hip_runtime.h>
#include <hip/hip_bf16.h>
#include <cstdint>
#include <cstddef>

#define T_SEQ 2048
#define CDIM  2048
#define HQ    16
#define HKV   4
#define DHEAD 128
#define NQKV  3072   // q(2048) | k(512) | v(512)

typedef __bf16 bf8 __attribute__((ext_vector_type(8)));
typedef __bf16 bf4 __attribute__((ext_vector_type(4)));
typedef float  f4  __attribute__((ext_vector_type(4)));

static __device__ __forceinline__ f4 mfma16(bf8 a, bf8 b, f4 c) {
    return __builtin_amdgcn_mfma_f32_16x16x32_bf16(a, b, c, 0, 0, 0);
}

#define GLOAD16(g, l)                                                        \
    __builtin_amdgcn_global_load_lds(                                        \
        (const __attribute__((address_space(1))) void*)(g),                  \
        (__attribute__((address_space(3))) void*)(l), 16, 0, 0)

// ---------------- fused prep: x->bf16, RoPE table, 4 weight transposes ----------------
__global__ __launch_bounds__(256) void k_pre(const float* __restrict__ x,
                                             const float* __restrict__ wq,
                                             const float* __restrict__ wk,
                                             const float* __restrict__ wv,
                                             const float* __restrict__ wo,
                                             __bf16* __restrict__ xbf,
                                             float* __restrict__ tab,
                                             __bf16* __restrict__ wqkvT,
                                             __bf16* __restrict__ woT) {
    const int bid = blockIdx.x, tid = threadIdx.x;
    if (bid < 4096) {
        int i = bid * 256 + tid;
        float4 v = ((const float4*)x)[i];
        bf4 o;
        o[0] = (__bf16)v.x; o[1] = (__bf16)v.y; o[2] = (__bf16)v.z; o[3] = (__bf16)v.w;
        ((bf4*)xbf)[i] = o;
        return;
    }
    if (bid < 4608) {
        int idx = (bid - 4096) * 256 + tid;  // T*64
        int t = idx >> 6, j = idx & 63;
        float invf = expf(-(float)j * (9.210340371976184f / 64.0f));
        float a = (float)t * invf;
        tab[idx * 2 + 0] = cosf(a);
        tab[idx * 2 + 1] = sinf(a);
        return;
    }
    __shared__ float tile[32][33];
    const int n = bid - 4608;
    const int bx = n % 160, by = n / 160;
    const float* src; __bf16* dst; int ld_src, cx;
    if (bx < 64)      { src = wq; dst = wqkvT;                        ld_src = 2048; cx = bx; }
    else if (bx < 80) { src = wk; dst = wqkvT + (size_t)2048 * 2048;  ld_src = 512;  cx = bx - 64; }
    else if (bx < 96) { src = wv; dst = wqkvT + (size_t)2560 * 2048;  ld_src = 512;  cx = bx - 80; }
    else              { src = wo; dst = woT;                          ld_src = 2048; cx = bx - 96; }
    const int c0 = cx * 32, r0 = by * 32;
    const int tx = tid & 31, ty = tid >> 5;
#pragma unroll
    for (int i = 0; i < 4; ++i)
        tile[ty + i * 8][tx] = src[(size_t)(r0 + ty + i * 8) * ld_src + c0 + tx];
    __syncthreads();
#pragma unroll
    for (int i = 0; i < 4; ++i)
        dst[(size_t)(c0 + ty + i * 8) * 2048 + r0 + tx] = (__bf16)tile[tx][ty + i * 8];
}

// ---------------- GEMM: C[M][N] = A[M][K] * BT[N][K]^T ----------------
// 512 thr / 8 waves (4 row x 2 col), per-wave acc[2][4] (32x128 output).
// BK=64 double-buffered global_load_lds, one barrier per K-step, XOR-swizzled LDS.
// MODE 0: fp32 C out. MODE 1: QKV fused epilogue -> RoPE'd Q/K + transposed VT.
// NOTE: no s_setprio — barrier-synced lockstep waves (m190: setprio hurts here).
template <int MODE>
__global__ __launch_bounds__(512, 4) void k_gemm(const __bf16* __restrict__ A,
                                                 const __bf16* __restrict__ BT,
                                                 float* __restrict__ C,
                                                 const float2* __restrict__ tab,
                                                 __bf16* __restrict__ Qo,
                                                 __bf16* __restrict__ Ko,
                                                 __bf16* __restrict__ Vo,
                                                 int M, int N, int K) {
    __shared__ __bf16 lds[2][2][128 * 64];   // [buf][mat][row*64], rows 128B
    char* L = (char*)&lds[0][0][0];
    const int tid = threadIdx.x, wid = tid >> 6, lane = tid & 63;
    const int l15 = lane & 15, lhi = lane >> 4;
    const int wr = wid >> 1, wc = wid & 1;
    const size_t arow0 = (size_t)blockIdx.y * 128;
    const size_t brow0 = (size_t)blockIdx.x * 128;

    const int sr = tid >> 3;
    const int sc8 = ((tid & 7) ^ ((tid >> 3) & 7)) * 8;
    const __bf16* Ag = A + (arow0 + sr) * K + sc8;
    const __bf16* Bg = BT + (brow0 + sr) * K + sc8;

#define GSTAGE(buf, k0)                                                          \
    {                                                                            \
        _Pragma("unroll") for (int i = 0; i < 2; ++i) {                          \
            GLOAD16(Ag + (k0) + (size_t)i * 64 * K,                              \
                    L + (buf) * 32768 + i * 8192 + tid * 16);                    \
            GLOAD16(Bg + (k0) + (size_t)i * 64 * K,                              \
                    L + (buf) * 32768 + 16384 + i * 8192 + tid * 16);            \
        }                                                                        \
    }

    f4 acc[2][4] = {};
    GSTAGE(0, 0);
    __syncthreads();
    int cur = 0;

    for (int k0 = 0; k0 < K; k0 += 64) {
        if (k0 + 64 < K) GSTAGE(cur ^ 1, k0 + 64);
        const char* Ab = L + cur * 32768;
        const char* Bb = Ab + 16384;
        bf8 af[2][2], bfr[2][4];
#pragma unroll
        for (int kk = 0; kk < 2; ++kk) {
            const int ch = ((kk * 4 + lhi) ^ (l15 & 7)) * 16;
#pragma unroll
            for (int m = 0; m < 2; ++m)
                af[kk][m] = *(const bf8*)(Ab + (wr * 32 + m * 16 + l15) * 128 + ch);
#pragma unroll
            for (int n = 0; n < 4; ++n)
                bfr[kk][n] = *(const bf8*)(Bb + (n * 32 + wc * 16 + l15) * 128 + ch);
        }
#pragma unroll
        for (int kk = 0; kk < 2; ++kk)
#pragma unroll
            for (int m = 0; m < 2; ++m)
#pragma unroll
                for (int n = 0; n < 4; ++n)
                    acc[m][n] = mfma16(af[kk][m], bfr[kk][n], acc[m][n]);
        __syncthreads();
        cur ^= 1;
    }
#undef GSTAGE

    const int row0 = blockIdx.y * 128 + wr * 32;
    if (MODE == 0) {
#pragma unroll
        for (int m = 0; m < 2; ++m)
#pragma unroll
            for (int n = 0; n < 4; ++n) {
                const int c = blockIdx.x * 128 + n * 32 + wc * 16 + l15;
#pragma unroll
                for (int j = 0; j < 4; ++j)
                    C[(size_t)(row0 + m * 16 + lhi * 4 + j) * N + c] = acc[m][n][j];
            }
    } else {
        const int bx = blockIdx.x;
        if (bx < 20) {
            // RoPE on fp32 acc: pair (n, n+2) = (d, d+64), d = n*32+wc*16+l15
            __bf16* dst0 = (bx < 16) ? (Qo + (size_t)bx * T_SEQ * DHEAD)
                                     : (Ko + (size_t)(bx - 16) * T_SEQ * DHEAD);
#pragma unroll
            for (int m = 0; m < 2; ++m)
#pragma unroll
                for (int n = 0; n < 2; ++n) {
                    const int d = n * 32 + wc * 16 + l15;
#pragma unroll
                    for (int j = 0; j < 4; ++j) {
                        const int t = row0 + m * 16 + lhi * 4 + j;
                        const float2 cs = tab[t * 64 + d];
                        const float a = acc[m][n][j], b = acc[m][n + 2][j];
                        dst0[(size_t)t * DHEAD + d]      = (__bf16)(a * cs.x - b * cs.y);
                        dst0[(size_t)t * DHEAD + d + 64] = (__bf16)(b * cs.x + a * cs.y);
                    }
                }
        } else {
            // V: write transposed VT[kvh][d][t], 4 consecutive t per lane
            __bf16* vdst = Vo + (size_t)(bx - 20) * DHEAD * T_SEQ;
#pragma unroll
            for (int m = 0; m < 2; ++m)
#pragma unroll
                for (int n = 0; n < 4; ++n) {
                    const int c = n * 32 + wc * 16 + l15;
                    bf4 o;
#pragma unroll
                    for (int j = 0; j < 4; ++j) o[j] = (__bf16)acc[m][n][j];
                    *(bf4*)&vdst[(size_t)c * T_SEQ + row0 + m * 16 + lhi * 4] = o;
                }
        }
    }
}

// ---------------- dual-softmax flash attention, key-split across wave halves ----------------
// grid (32,16) x 512 thr (8 waves). Waves 0-3: even key tiles; 4-7: odd key tiles,
// same 64 q-rows. Per-half online softmax; exact merge at end. K/V double-buffered
// 128-key rounds via global_load_lds (pre-swizzled source).
// NO s_setprio in the round loop: with 2 barrier-locked waves/SIMD, prioritizing
// one wave's MFMA window serializes the two chains (m190 mechanism).
__global__ __launch_bounds__(512) void k_attn(const __bf16* __restrict__ Q,
                                              const __bf16* __restrict__ Kr,
                                              const __bf16* __restrict__ VT,
                                              __bf16* __restrict__ att) {
    __shared__ __align__(16) char lds[155648];
    char* KlB  = lds;               // [2][128 keys][256B d], 4-bit row XOR swz
    char* VlB  = lds + 65536;       // [2][128 d][256B keys], 4-bit row XOR swz
    char* PlB0 = lds + 131072;      // 8 waves x 2KB
    char* PwB0 = lds + 147456;      // 4 qw x 2KB (parity-active waves only)

    const int h = blockIdx.y, kvh = h >> 2;
    const int qt = (blockIdx.y < 8) ? (31 - (int)blockIdx.x) : (int)blockIdx.x;
    const int tid = threadIdx.x, wid = tid >> 6, lane = tid & 63;
    const int l15 = lane & 15, lhi = lane >> 4;
    const int par = wid >> 2, qw = wid & 3;
    const int q0w = qt * 64 + qw * 16;
    const bool hasloc = qt >= 4;
    const int lfLo = 4 * (qt >> 2) - 2;
    const int lpart = qt - 2;
    const float CE = 0.12751741f;                // (1/sqrt(128)) * log2(e)
    const float L2E = 1.44269504f;
    const float SCL = 0.08838834764831845f;
    const float THR = 5.5451774f;                // 8*ln2

    char* PlB = PlB0 + wid * 2048;
    char* PwB = PwB0 + qw * 2048;

    const int srow = tid >> 4;                        // 0..31
    const int sg = (((tid & 15) ^ (srow & 15)) << 3); // elem offset
    const __bf16* KgB = Kr + (size_t)kvh * T_SEQ * DHEAD;
    const __bf16* VgB = VT + (size_t)kvh * DHEAD * T_SEQ;

#define STAGE(bsel, kb2)                                                          \
    {                                                                             \
        _Pragma("unroll") for (int i = 0; i < 4; ++i) {                           \
            GLOAD16(KgB + (size_t)((kb2) + i * 32 + srow) * DHEAD + sg,           \
                    KlB + (bsel) + i * 8192 + tid * 16);                          \
            GLOAD16(VgB + (size_t)(i * 32 + srow) * T_SEQ + (kb2) + sg,           \
                    VlB + (bsel) + i * 8192 + tid * 16);                          \
        }                                                                         \
    }

    bf8 qf[4];
#pragma unroll
    for (int dc = 0; dc < 4; ++dc)
        qf[dc] = *(const bf8*)&Q[((size_t)h * T_SEQ + q0w + l15) * DHEAD + dc * 32 + lhi * 8];

    f4 oc[8] = {}, ow[8] = {};
    float mg[4], sgp[4], slp[4];
#pragma unroll
    for (int j = 0; j < 4; ++j) { mg[j] = -__builtin_inff(); sgp[j] = slp[j] = 0.f; }
    float mgmin = -__builtin_inff();

    const int R = (qt >> 1) + 1;
    STAGE(0, 0);
    __syncthreads();
    int cur = 0;

    for (int r = 0; r < R; ++r) {
        if (r + 1 < R) STAGE((cur ^ 1) * 32768, (r + 1) * 128);
        const int kt = 2 * r + par;
        if (kt <= qt) {
            const int kb = kt * 64;
            const int cb = cur * 32768;
            const int rowb = par * 64;
            // ---- QK^T ----
            f4 sc[4] = {};
#pragma unroll
            for (int ks = 0; ks < 4; ++ks)
#pragma unroll
                for (int dc = 0; dc < 4; ++dc) {
                    bf8 kf = *(const bf8*)(KlB + cb + (rowb + ks * 16 + l15) * 256 +
                                           (((dc * 4 + lhi) ^ l15) << 4));
                    sc[ks] = mfma16(qf[dc], kf, sc[ks]);
                }

            float t[4][4];
#pragma unroll
            for (int ks = 0; ks < 4; ++ks)
#pragma unroll
                for (int j = 0; j < 4; ++j) t[ks][j] = sc[ks][j];
            if (kt == qt) {  // causal mask (last tile only)
#pragma unroll
                for (int ks = 0; ks < 4; ++ks)
#pragma unroll
                    for (int j = 0; j < 4; ++j)
                        if (kb + ks * 16 + l15 > q0w + lhi * 4 + j) t[ks][j] = -3.0e38f;
            }
            // ---- single defer-max gate ----
            float mx = t[0][0];
#pragma unroll
            for (int ks = 0; ks < 4; ++ks)
#pragma unroll
                for (int j = 0; j < 4; ++j) mx = fmaxf(mx, t[ks][j]);
            mx *= SCL;
            if (!__all(mx <= mgmin + THR)) {
#pragma unroll
                for (int j = 0; j < 4; ++j) {
                    float m2 = fmaxf(fmaxf(t[0][j], t[1][j]), fmaxf(t[2][j], t[3][j])) * SCL;
#pragma unroll
                    for (int x = 1; x < 16; x <<= 1) m2 = fmaxf(m2, __shfl_xor(m2, x));
                    float mn = fmaxf(mg[j], m2);
                    float f = __builtin_amdgcn_exp2f((mg[j] - mn) * L2E);
                    mg[j] = mn;
                    sgp[j] *= f; slp[j] *= f;
#pragma unroll
                    for (int nd = 0; nd < 8; ++nd) { oc[nd][j] *= f; ow[nd][j] *= f; }
                }
                mgmin = fminf(fminf(mg[0], mg[1]), fminf(mg[2], mg[3]));
            }
            // ---- branch-free exp ----
            float p[4][4], psum[4];
#pragma unroll
            for (int j = 0; j < 4; ++j) {
                const float bj = mg[j] * L2E;
#pragma unroll
                for (int ks = 0; ks < 4; ++ks)
                    p[ks][j] = __builtin_amdgcn_exp2f(t[ks][j] * CE - bj);
                psum[j] = (p[0][j] + p[1][j]) + (p[2][j] + p[3][j]);
                sgp[j] += psum[j];
            }
            // ---- P stores ----
            const bool part = hasloc && (kt == lpart);
            if (!part) {
#pragma unroll
                for (int j = 0; j < 4; ++j) {
                    const int rsw = ((lhi * 4 + j) & 7) << 4;
                    const int rb = (lhi * 4 + j) * 128;
#pragma unroll
                    for (int ks = 0; ks < 4; ++ks)
                        *(__bf16*)(PlB + rb + ((ks * 32 + 2 * l15) ^ rsw)) = (__bf16)p[ks][j];
                }
            } else {
                const int e = q0w + lhi * 4 - 128 - kb - l15;
#pragma unroll
                for (int j = 0; j < 4; ++j) {
                    const int rsw = ((lhi * 4 + j) & 7) << 4;
                    const int rb = (lhi * 4 + j) * 128;
                    float lsum = 0.f;
#pragma unroll
                    for (int ks = 0; ks < 4; ++ks) {
                        float l = (ks * 16 <= e + j) ? p[ks][j] : 0.f;
                        lsum += l;
                        *(__bf16*)(PwB + rb + ((ks * 32 + 2 * l15) ^ rsw)) = (__bf16)l;
                        *(__bf16*)(PlB + rb + ((ks * 32 + 2 * l15) ^ rsw)) = (__bf16)(p[ks][j] - l);
                    }
                    slp[j] += lsum;
                }
            }
            const bool inwin = hasloc && kt >= lfLo && kt < lpart;
            if (inwin) {
#pragma unroll
                for (int j = 0; j < 4; ++j) slp[j] += psum[j];
            }
            // ---- PV ----
            const int psw = (l15 & 7) << 4;
            bf8 pf0 = *(const bf8*)(PlB + l15 * 128 + ((lhi << 4) ^ psw));
            bf8 pf1 = *(const bf8*)(PlB + l15 * 128 + ((64 + (lhi << 4)) ^ psw));
            const int vg0 = ((par * 8 + lhi) ^ l15) << 4;
            const int vg1 = ((par * 8 + 4 + lhi) ^ l15) << 4;
            if (part) {
                bf8 pw0 = *(const bf8*)(PwB + l15 * 128 + ((lhi << 4) ^ psw));
                bf8 pw1 = *(const bf8*)(PwB + l15 * 128 + ((64 + (lhi << 4)) ^ psw));
#pragma unroll
                for (int nd = 0; nd < 8; ++nd) {
                    bf8 v0 = *(const bf8*)(VlB + cb + (nd * 16 + l15) * 256 + vg0);
                    bf8 v1 = *(const bf8*)(VlB + cb + (nd * 16 + l15) * 256 + vg1);
                    oc[nd] = mfma16(pf0, v0, oc[nd]);
                    oc[nd] = mfma16(pf1, v1, oc[nd]);
                    ow[nd] = mfma16(pw0, v0, ow[nd]);
                    ow[nd] = mfma16(pw1, v1, ow[nd]);
                }
            } else if (inwin) {
#pragma unroll
                for (int nd = 0; nd < 8; ++nd) {
                    bf8 v0 = *(const bf8*)(VlB + cb + (nd * 16 + l15) * 256 + vg0);
                    bf8 v1 = *(const bf8*)(VlB + cb + (nd * 16 + l15) * 256 + vg1);
                    ow[nd] = mfma16(pf0, v0, ow[nd]);
                    ow[nd] = mfma16(pf1, v1, ow[nd]);
                }
            } else {
#pragma unroll
                for (int nd = 0; nd < 8; ++nd) {
                    bf8 v0 = *(const bf8*)(VlB + cb + (nd * 16 + l15) * 256 + vg0);
                    bf8 v1 = *(const bf8*)(VlB + cb + (nd * 16 + l15) * 256 + vg1);
                    oc[nd] = mfma16(pf0, v0, oc[nd]);
                    oc[nd] = mfma16(pf1, v1, oc[nd]);
                }
            }
        }
        __syncthreads();   // drains staging (vmcnt 0) + frees cur buffer
        cur ^= 1;
    }

    // ---- split-softmax merge: waves 4-7 -> LDS, waves 0-3 combine ----
    // field-major scratch: field*4096 + (qw*64+lane)*16 -> consecutive lanes
    // contiguous 16B => conflict-free. 19 fields * 4KB = 76KB (K/V region dead).
    char* sb = lds + (size_t)(qw * 64 + lane) * 16;
    if (par) {
#pragma unroll
        for (int nd = 0; nd < 8; ++nd) *(f4*)(sb + nd * 4096) = oc[nd];
#pragma unroll
        for (int nd = 0; nd < 8; ++nd) *(f4*)(sb + (8 + nd) * 4096) = ow[nd];
        f4 a, b, c;
#pragma unroll
        for (int j = 0; j < 4; ++j) { a[j] = mg[j]; b[j] = sgp[j]; c[j] = slp[j]; }
        *(f4*)(sb + 16 * 4096) = a; *(f4*)(sb + 17 * 4096) = b; *(f4*)(sb + 18 * 4096) = c;
    }
    __syncthreads();
    if (!par) {
        f4 mB = *(const f4*)(sb + 16 * 4096);
        f4 sB = *(const f4*)(sb + 17 * 4096);
        f4 lB = *(const f4*)(sb + 18 * 4096);
        float fA[4], fB[4];
#pragma unroll
        for (int j = 0; j < 4; ++j) {
            float ms = fmaxf(mg[j], mB[j]);
            fA[j] = __builtin_amdgcn_exp2f((mg[j] - ms) * L2E);
            fB[j] = __builtin_amdgcn_exp2f((mB[j] - ms) * L2E);
            sgp[j] = sgp[j] * fA[j] + sB[j] * fB[j];
            slp[j] = slp[j] * fA[j] + lB[j] * fB[j];
        }
#pragma unroll
        for (int nd = 0; nd < 8; ++nd) {
            f4 ocB = *(const f4*)(sb + nd * 4096);
            f4 owB = *(const f4*)(sb + (8 + nd) * 4096);
#pragma unroll
            for (int j = 0; j < 4; ++j) {
                oc[nd][j] = oc[nd][j] * fA[j] + ocB[j] * fB[j];
                ow[nd][j] = ow[nd][j] * fA[j] + owB[j] * fB[j];
            }
        }
#pragma unroll
        for (int j = 0; j < 4; ++j) {
#pragma unroll
            for (int x = 1; x < 16; x <<= 1) {
                sgp[j] += __shfl_xor(sgp[j], x);
                slp[j] += __shfl_xor(slp[j], x);
            }
        }
        float rg[4], rl[4];
#pragma unroll
        for (int j = 0; j < 4; ++j) {
            rg[j] = 1.f / sgp[j];
            rl[j] = hasloc ? 0.5f / slp[j] : 0.f;
        }
#pragma unroll
        for (int nd = 0; nd < 8; ++nd)
#pragma unroll
            for (int j = 0; j < 4; ++j) {
                int q = q0w + lhi * 4 + j;
                float go = oc[nd][j] + ow[nd][j];
                float v = hasloc ? (go * (0.5f * rg[j]) + ow[nd][j] * rl[j]) : go * rg[j];
                att[(size_t)q * CDIM + h * DHEAD + nd * 16 + l15] = (__bf16)v;
            }
    }
#undef STAGE
}

// ---------------- launcher ----------------
extern "C" void kernel_launch(void* const* d_in, const int* in_sizes, int n_in,
                              void* d_out, int out_size, void* d_ws, size_t ws_size,
                              hipStream_t stream) {
    const float* x  = (const float*)d_in[0];
    const float* wq = (const float*)d_in[1];
    const float* wk = (const float*)d_in[2];
    const float* wv = (const float*)d_in[3];
    const float* wo = (const float*)d_in[4];
    char* ws = (char*)d_ws;

    __bf16* xbf   = (__bf16*)(ws + 0);          // 8 MB
    __bf16* wqkvT = (__bf16*)(ws + 8388608);    // 12 MB  [3072][2048]
    __bf16* woT   = (__bf16*)(ws + 20971520);   // 8 MB   [2048][2048]
    __bf16* Q     = (__bf16*)(ws + 41943040);   // 8 MB   [16][2048][128]
    __bf16* K     = (__bf16*)(ws + 50331648);   // 2 MB   [4][2048][128]
    __bf16* VTb   = (__bf16*)(ws + 52428800);   // 2 MB   [4][128][2048]
    __bf16* att   = (__bf16*)(ws + 54525952);   // 8 MB   [2048][2048]
    float*  tab   = (float*)(ws + 62914560);    // 1 MB   [2048][64][2]

    k_pre<<<14848, 256, 0, stream>>>(x, wq, wk, wv, wo, xbf, tab, wqkvT, woT);
    k_gemm<1><<<dim3(24, 16), 512, 0, stream>>>(xbf, wqkvT, nullptr, (const float2*)tab,
                                                Q, K, VTb, 2048, 3072, 2048);
    k_attn<<<dim3(32, 16), 512, 0, stream>>>(Q, K, VTb, att);
    k_gemm<0><<<dim3(16, 16), 512, 0, stream>>>(att, woT, (float*)d_out, nullptr,
                                                nullptr, nullptr, nullptr, 2048, 2048, 2048);
}